// Round 8
// baseline (196.499 us; speedup 1.0000x reference)
//
#include <hip/hip_runtime.h>
#include <hip/hip_bf16.h>
#include <math.h>

#define L_SEQ 8192
#define B_BATCH 8
#define D_DIM 256
#define BL (B_BATCH * L_SEQ)
#define EPS_F 1.1920929e-07f

typedef __attribute__((ext_vector_type(8))) short short8;
typedef __attribute__((ext_vector_type(4))) float f32x4;
typedef __attribute__((ext_vector_type(4))) unsigned short u16x4;

// ws layout (bytes):
//   [0,       262144)  starts int32 BL (k_scan+)
//   [262144,  524288)  Bpack bf16: 2 segs (M1,M2) x 8 k8 x 16 ct fragments x 64 lanes x 8
//   [524288,  589824)  hard  uint8  BL
//   [589824,  589856)  n_b   int32  8
//   [589856,  589888)  len   int32  8
// out reuse (before their final producers run):
//   pooled [64 MB]  <- hiG (32 MB) + loG (32 MB)   (dead after k_cosmfma; k_pool rewrites)
//   shortm [256 KB] <- dotsG fp32 BL               (dead after k_cosmfma; k_scan rewrites)

__device__ inline unsigned short f2bf(float x) {
    __hip_bfloat16 b = __float2bfloat16(x);
    return *(unsigned short*)&b;
}
__device__ inline float bf2f(unsigned short u) {
    __hip_bfloat16 b = *(__hip_bfloat16*)&u;
    return __bfloat162float(b);
}

// ------------------- K1: fused M = Wq^T*Wk - I  ->  bf16 hi/lo MFMA B-fragment pack
__global__ __launch_bounds__(256) void k_matMpack(
    const float* __restrict__ Wq, const float* __restrict__ Wk,
    unsigned short* __restrict__ Bpack) {
    __shared__ float Aq[64][33];
    __shared__ float Ak[64][17];
    const int f   = blockIdx.x;       // 0..127
    const int k8  = f >> 4, ct = f & 15;
    const int tid = threadIdx.x;
    const int n   = tid & 15;         // col within ct tile
    const int k   = tid >> 4;         // 0..15; thread owns rows k and k+16 of the strip
    float a0 = 0.f, a1 = 0.f;
    for (int e0 = 0; e0 < 256; e0 += 64) {
        for (int i = tid; i < 64 * 32; i += 256) {
            const int e = i >> 5, d = i & 31;
            Aq[e][d] = Wq[(e0 + e) * 256 + k8 * 32 + d];
        }
        for (int i = tid; i < 64 * 16; i += 256) {
            const int e = i >> 4, d = i & 15;
            Ak[e][d] = Wk[(e0 + e) * 256 + ct * 16 + d];
        }
        __syncthreads();
#pragma unroll 8
        for (int e = 0; e < 64; ++e) {
            a0 += Aq[e][k] * Ak[e][n];
            a1 += Aq[e][k + 16] * Ak[e][n];
        }
        __syncthreads();
    }
    const int col = ct * 16 + n;
    const float M0 = a0 - ((k8 * 32 + k)      == col ? 1.0f : 0.0f);
    const float M1 = a1 - ((k8 * 32 + k + 16) == col ? 1.0f : 0.0f);
    const unsigned short h0 = f2bf(M0), h1 = f2bf(M1);
    const unsigned short l0 = f2bf(M0 - bf2f(h0)), l1 = f2bf(M1 - bf2f(h1));
    unsigned short* dstH = Bpack + (size_t)(k8 * 16 + ct) * 512;
    unsigned short* dstL = dstH + 128 * 512;
    const int q0 = k >> 3, j0 = k & 7;
    const int q1 = (k + 16) >> 3;
    dstH[(q0 * 16 + n) * 8 + j0] = h0;
    dstH[(q1 * 16 + n) * 8 + j0] = h1;
    dstL[(q0 * 16 + n) * 8 + j0] = l0;
    dstL[(q1 * 16 + n) * 8 + j0] = l1;
}

// ---------------- K2 (new): pre-normalize -> bf16 hi/lo to global + exact pair dots
// v8: hoists the normalize/convert/dot chains OUT of the tiled MFMA kernel. 8192
// waves (8 tok/wave) -> 8 waves/SIMD TLP fully hides the shfl-chain latency that
// dominated v7's k_cosmfma (staging was ~720 VALU + 108 serialized ds_bpermute per
// wave, replicated in every block). Bit-identical arithmetic to the old staging.
__global__ __launch_bounds__(256) void k_prenorm(
    const float* __restrict__ hidden, unsigned short* __restrict__ hiG,
    unsigned short* __restrict__ loG, float* __restrict__ dotsG) {
    const int tid  = threadIdx.x;
    const int lane = tid & 63;
    const int w    = tid >> 6;
    const int t0   = (blockIdx.x * 4 + w) * 8;   // wave's first token
    int tokA = t0 - 1; if (tokA < 0) tokA = 0;
    float4 vb0 = ((const float4*)hidden)[(size_t)tokA * 64 + lane];
    float4 vb1 = ((const float4*)hidden)[(size_t)t0 * 64 + lane];
    float4 hp4 = {0.f, 0.f, 0.f, 0.f};
#pragma unroll 1
    for (int ii = 0; ii <= 8; ++ii) {
        const float4 vcur = vb0;
        vb0 = vb1;
        if (ii + 2 <= 8)   // prefetch token t0 + ii + 1
            vb1 = ((const float4*)hidden)[(size_t)(t0 + ii + 1) * 64 + lane];
        float ss = vcur.x * vcur.x + vcur.y * vcur.y + vcur.z * vcur.z + vcur.w * vcur.w;
#pragma unroll
        for (int sh = 32; sh >= 1; sh >>= 1) ss += __shfl_xor(ss, sh);
        const float inv = 1.0f / fmaxf(sqrtf(ss), 1e-12f);
        float4 h4;
        h4.x = vcur.x * inv; h4.y = vcur.y * inv;
        h4.z = vcur.z * inv; h4.w = vcur.w * inv;
        const unsigned short hx = f2bf(h4.x), hy = f2bf(h4.y),
                             hz = f2bf(h4.z), hw2 = f2bf(h4.w);
        const u16x4 hv4 = {hx, hy, hz, hw2};
        const u16x4 lv4 = {f2bf(h4.x - bf2f(hx)), f2bf(h4.y - bf2f(hy)),
                           f2bf(h4.z - bf2f(hz)), f2bf(h4.w - bf2f(hw2))};
        if (ii > 0) {
            const int tok = t0 - 1 + ii;    // tokens t0 .. t0+7, each written once
            *(u16x4*)&hiG[(size_t)tok * 256 + lane * 4] = hv4;
            *(u16x4*)&loG[(size_t)tok * 256 + lane * 4] = lv4;
            // exact fp32 dot hn_{tok-1}.hn_tok  (unused when tok % L_SEQ == 0)
            float pd = h4.x * hp4.x + h4.y * hp4.y + h4.z * hp4.z + h4.w * hp4.w;
#pragma unroll
            for (int sh = 32; sh >= 1; sh >>= 1) pd += __shfl_xor(pd, sh);
            if (lane == 0) dotsG[tok] = pd;
        }
        hp4 = h4;
    }
}

// ------------------------------ K3: MFMA correction GEMM + cos + hard bit
// v8: staging is now a pure copy (18 independent 8B loads/lane, no chains, no
// converts); dots read from global. Main loop & epilogue identical to v7.
#define RS 264   // LDS row stride in bf16 elems: 528 B
#define MM(A,Bv,C) __builtin_amdgcn_mfma_f32_16x16x32_bf16((A),(Bv),(C),0,0,0)
#define MFMA8(V0,V1,BN) \
    acc[0][0]=MM(V0,BN##_0,acc[0][0]); acc[0][1]=MM(V0,BN##_1,acc[0][1]); \
    acc[0][2]=MM(V0,BN##_2,acc[0][2]); acc[0][3]=MM(V0,BN##_3,acc[0][3]); \
    acc[1][0]=MM(V1,BN##_0,acc[1][0]); acc[1][1]=MM(V1,BN##_1,acc[1][1]); \
    acc[1][2]=MM(V1,BN##_2,acc[1][2]); acc[1][3]=MM(V1,BN##_3,acc[1][3]);
#define LOADB(BN,S) \
    BN##_0 = Bld[(((S) * 16) + wc4 + 0) * 64]; \
    BN##_1 = Bld[(((S) * 16) + wc4 + 1) * 64]; \
    BN##_2 = Bld[(((S) * 16) + wc4 + 2) * 64]; \
    BN##_3 = Bld[(((S) * 16) + wc4 + 3) * 64];
#define STRIP_HL(S,BN) { \
    const int co = ((S) & 7) * 32; \
    const short8 hv0 = *(const short8*)(hA0 + co), hv1 = *(const short8*)(hA1 + co); \
    const short8 lv0 = *(const short8*)(lA0 + co), lv1 = *(const short8*)(lA1 + co); \
    MFMA8(hv0, hv1, BN); \
    MFMA8(lv0, lv1, BN); \
    LOADB(BN, (S) + 3); }
#define STRIP_H(S,BN) { \
    const int co = ((S) & 7) * 32; \
    const short8 hv0 = *(const short8*)(hA0 + co), hv1 = *(const short8*)(hA1 + co); \
    MFMA8(hv0, hv1, BN); \
    if ((S) + 3 < 16) { LOADB(BN, (S) + 3); } }

__global__ __launch_bounds__(256, 2) void k_cosmfma(
    const unsigned short* __restrict__ hiG, const unsigned short* __restrict__ loG,
    const float* __restrict__ dotsG, const unsigned short* __restrict__ Bpack,
    const float* __restrict__ noise, unsigned char* __restrict__ hard) {
    __shared__ __attribute__((aligned(16))) unsigned short hiA[33 * RS]; // 17,424 B
    __shared__ __attribute__((aligned(16))) unsigned short loA[33 * RS]; // 17,424 B
    __shared__ float Vpart[4][32];                                       //    512 B

    const int tid  = threadIdx.x;
    const int lane = tid & 63;
    const int w    = tid >> 6;        // wave 0..3
    const int wc4  = w * 4;           // ct base: cols [w*64, w*64+64)
    const int T0   = blockIdx.x * 32;

    const short8* __restrict__ Bld = (const short8*)Bpack + lane;

    // 3-buffer B pipeline; preload strips 0,1,2 (fly during staging)
    short8 bA_0, bA_1, bA_2, bA_3, bB_0, bB_1, bB_2, bB_3, bC_0, bC_1, bC_2, bC_3;
    LOADB(bA, 0);
    LOADB(bB, 1);
    LOADB(bC, 2);

    // ---- stage rows [w*8, w*8+8] (token max(T0-1+row,0)) by pure copy ----
    {
        const int r0 = w * 8;
#pragma unroll
        for (int ii = 0; ii <= 8; ++ii) {
            const int i = r0 + ii;
            int tok = T0 - 1 + i; if (tok < 0) tok = 0;
            const uint2 hv = ((const uint2*)(hiG + (size_t)tok * 256))[lane];
            const uint2 lv = ((const uint2*)(loG + (size_t)tok * 256))[lane];
            *(uint2*)&hiA[i * RS + lane * 4] = hv;
            *(uint2*)&loA[i * RS + lane * 4] = lv;
        }
    }
    __syncthreads();   // waves read other waves' slab rows below

    // A-frag pointers: frag af covers slab rows af*16 + m; lane holds A[m][q*8+j]
    const int m = lane & 15, q = lane >> 4;
    const unsigned short* __restrict__ hA0 = &hiA[( 0 + m) * RS + q * 8];
    const unsigned short* __restrict__ hA1 = &hiA[(16 + m) * RS + q * 8];
    const unsigned short* __restrict__ lA0 = &loA[( 0 + m) * RS + q * 8];
    const unsigned short* __restrict__ lA1 = &loA[(16 + m) * RS + q * 8];

    f32x4 acc[2][4];
#pragma unroll
    for (int af = 0; af < 2; ++af)
#pragma unroll
        for (int c = 0; c < 4; ++c) { f32x4 z = {0.f, 0.f, 0.f, 0.f}; acc[af][c] = z; }

    // strips 0..7: seg0 (hi B; A h+l); strips 8..15: seg1 (lo B; A h only)
    STRIP_HL(0, bA)  STRIP_HL(1, bB)  STRIP_HL(2, bC)  STRIP_HL(3, bA)
    STRIP_HL(4, bB)  STRIP_HL(5, bC)  STRIP_HL(6, bA)  STRIP_HL(7, bB)
    STRIP_H (8, bC)  STRIP_H (9, bA)  STRIP_H (10, bB) STRIP_H (11, bC)
    STRIP_H (12, bA) STRIP_H (13, bB) STRIP_H (14, bC) STRIP_H (15, bA)

    // ---- epilogue: per-row partial over this wave's 64 cols, then cross-wave reduce ----
    // D row = af*16 + q*4 + r (token T0+row), D col = (wc4+c)*16 + m.
#pragma unroll
    for (int af = 0; af < 2; ++af) {
#pragma unroll
        for (int r = 0; r < 4; ++r) {
            const int row = af * 16 + (q << 2) + r;
            const int ib  = (row + 1) * RS + wc4 * 16 + m;
            float pp = acc[af][0][r] * (bf2f(hiA[ib     ]) + bf2f(loA[ib     ]))
                     + acc[af][1][r] * (bf2f(hiA[ib + 16]) + bf2f(loA[ib + 16]))
                     + acc[af][2][r] * (bf2f(hiA[ib + 32]) + bf2f(loA[ib + 32]))
                     + acc[af][3][r] * (bf2f(hiA[ib + 48]) + bf2f(loA[ib + 48]));
            pp += __shfl_xor(pp, 1);
            pp += __shfl_xor(pp, 2);
            pp += __shfl_xor(pp, 4);
            pp += __shfl_xor(pp, 8);
            if (m == 0) Vpart[w][row] = pp;
        }
    }
    __syncthreads();
    if (tid < 32) {
        const int rl = tid;             // token t = T0 + rl
        const float part = Vpart[0][rl] + Vpart[1][rl] + Vpart[2][rl] + Vpart[3][rl];
        const int t = T0 + rl;
        const int l = t & (L_SEQ - 1);
        float p;
        if (l == 0) {
            p = 1.0f;
        } else {
            p = (1.0f - (part + dotsG[t])) * 0.5f;
            p = fminf(fmaxf(p, 0.0f), 1.0f);
        }
        p = fminf(fmaxf(p, EPS_F), 1.0f - EPS_F);
        float u = noise[t];
        u = fminf(fmaxf(u, EPS_F), 1.0f - EPS_F);
        const float z = ((logf(p) - log1pf(-p)) + logf(u)) - log1pf(-u);
        hard[t] = (z > 0.0f) ? (unsigned char)1 : (unsigned char)0;
    }
}

// ---------------------- K4: per-row length, forced boundary, scan -> starts, n_b, mask
__global__ __launch_bounds__(1024) void k_scan(
    const float* __restrict__ mask, const unsigned char* __restrict__ hard,
    int* __restrict__ starts, int* __restrict__ nb_arr,
    int* __restrict__ len_arr, float* __restrict__ out_short) {
    __shared__ int wsum[16];
    __shared__ int s_len;
    const int b = blockIdx.x, tid = threadIdx.x;
    const int lane = tid & 63, wv = tid >> 6;   // 16 waves
    const int base = b * L_SEQ;

    // row length = sum(mask): 8 floats per thread
    const float4* m4 = (const float4*)(mask + base);
    const float4 va = m4[tid * 2], vb = m4[tid * 2 + 1];
    int cnt = (va.x != 0.f) + (va.y != 0.f) + (va.z != 0.f) + (va.w != 0.f)
            + (vb.x != 0.f) + (vb.y != 0.f) + (vb.z != 0.f) + (vb.w != 0.f);
#pragma unroll
    for (int sh = 32; sh >= 1; sh >>= 1) cnt += __shfl_xor(cnt, sh);
    if (lane == 0) wsum[wv] = cnt;
    __syncthreads();
    if (tid == 0) {
        int s = 0;
        for (int i = 0; i < 16; ++i) s += wsum[i];
        s_len = s;
    }
    __syncthreads();
    const int len = s_len;

    // adjusted hard bits for this thread's 8 tokens [8*tid, 8*tid+8)
    const int i0 = tid * 8;
    const uint2 hb = ((const uint2*)(hard + base))[tid];
    int c = 0;
    unsigned int bits = 0;
#pragma unroll
    for (int j = 0; j < 8; ++j) {
        const unsigned int byte = ((j < 4 ? hb.x : hb.y) >> (8 * (j & 3))) & 0xffu;
        int h = ((i0 + j) < len) ? (int)(byte != 0u) : 0;
        if (len < L_SEQ && (i0 + j) == len - 1) h = 1;  // forced boundary at last real token
        bits |= (unsigned int)h << j;
        c += h;
    }
    // inclusive wave scan of counts
    int x = c;
#pragma unroll
    for (int ofs = 1; ofs < 64; ofs <<= 1) {
        const int t = __shfl_up(x, ofs);
        if (lane >= ofs) x += t;
    }
    if (lane == 63) wsum[wv] = x;
    __syncthreads();
    int woff = 0, nb = 0;
#pragma unroll
    for (int i = 0; i < 16; ++i) {
        const int t = wsum[i];
        nb += t;
        if (i < wv) woff += t;
    }
    int run = woff + x - c;   // exclusive prefix for this thread
#pragma unroll
    for (int j = 0; j < 8; ++j)
        if ((bits >> j) & 1u) { starts[base + run] = i0 + j; ++run; }

    if (tid == 0) { nb_arr[b] = nb; len_arr[b] = len; }

    float4 o0, o1;
    o0.x = (i0 + 0) < nb ? 1.f : 0.f; o0.y = (i0 + 1) < nb ? 1.f : 0.f;
    o0.z = (i0 + 2) < nb ? 1.f : 0.f; o0.w = (i0 + 3) < nb ? 1.f : 0.f;
    o1.x = (i0 + 4) < nb ? 1.f : 0.f; o1.y = (i0 + 5) < nb ? 1.f : 0.f;
    o1.z = (i0 + 6) < nb ? 1.f : 0.f; o1.w = (i0 + 7) < nb ? 1.f : 0.f;
    float4* os4 = (float4*)(out_short + base);
    os4[tid * 2] = o0;
    os4[tid * 2 + 1] = o1;
}

// ------------------- K5: one wave per segment, mean-pool (+ fused scalars/loss)
__global__ __launch_bounds__(256) void k_pool(
    const float* __restrict__ hidden, const int* __restrict__ starts,
    const int* __restrict__ nb_arr, const int* __restrict__ len_arr,
    float* __restrict__ pooled, float* __restrict__ out_scal) {
    const int tid  = threadIdx.x;
    const int lane = tid & 63;
    const int wid  = blockIdx.x * 4 + (tid >> 6);
    const int b    = wid >> 13;       // / 8192
    const int s    = wid & (L_SEQ - 1);
    const int nb   = nb_arr[b];

    if (blockIdx.x == 0 && tid == 0) {   // fused k_final (nb/len ready from k_scan)
        int nbt = 0, ln = 0;
        for (int i = 0; i < B_BATCH; ++i) { nbt += nb_arr[i]; ln += len_arr[i]; }
        const double k = (double)nbt, n = (double)ln;
        const double logp = lgamma(n + 1.0) - lgamma(k + 1.0) - lgamma(n - k + 1.0)
                            + k * log(0.2) + (n - k) * log(0.8);
        out_scal[0] = (float)(-logp / n);
        out_scal[1] = (float)nbt;
        out_scal[2] = (float)ln;
    }

    float4 res = {0.f, 0.f, 0.f, 0.f};
    if (s < nb) {
        const int start = (s == 0) ? 0 : starts[b * L_SEQ + s];
        const int end   = (s + 1 < nb) ? starts[b * L_SEQ + s + 1] : len_arr[b];
        float4 acc = {0.f, 0.f, 0.f, 0.f};
        for (int t = start; t < end; ++t) {
            const float4 v = ((const float4*)hidden)[(b * L_SEQ + t) * 64 + lane];
            acc.x += v.x; acc.y += v.y; acc.z += v.z; acc.w += v.w;
        }
        const float cntf = (float)(end - start);
        res.x = acc.x / cntf; res.y = acc.y / cntf; res.z = acc.z / cntf; res.w = acc.w / cntf;
    }
    ((float4*)pooled)[(size_t)wid * 64 + lane] = res;
}

extern "C" void kernel_launch(void* const* d_in, const int* in_sizes, int n_in,
                              void* d_out, int out_size, void* d_ws, size_t ws_size,
                              hipStream_t stream) {
    const float* hidden = (const float*)d_in[0];
    const float* Wq     = (const float*)d_in[1];
    const float* Wk     = (const float*)d_in[2];
    const float* noise  = (const float*)d_in[3];
    const float* mask   = (const float*)d_in[4];
    float* out = (float*)d_out;
    char* ws = (char*)d_ws;

    int*            starts = (int*)(ws);
    unsigned short* Bpack  = (unsigned short*)(ws + 262144);
    unsigned char*  hard   = (unsigned char*)(ws + 524288);
    int*            nb_arr = (int*)(ws + 589824);
    int*            len_arr= (int*)(ws + 589856);

    float* pooled = out;
    float* scal   = out + (size_t)BL * D_DIM;
    float* shortm = scal + 3;

    // transient reuse of the output buffer (all dead before their final producers):
    unsigned short* hiG   = (unsigned short*)out;            // 32 MB
    unsigned short* loG   = hiG + (size_t)BL * 256;          // 32 MB
    float*          dotsG = shortm;                          // 256 KB

    k_matMpack<<<128, 256, 0, stream>>>(Wq, Wk, Bpack);
    k_prenorm <<<BL / 32, 256, 0, stream>>>(hidden, hiG, loG, dotsG);
    k_cosmfma <<<BL / 32, 256, 0, stream>>>(hiG, loG, dotsG, Bpack, noise, hard);
    k_scan    <<<B_BATCH, 1024, 0, stream>>>(mask, hard, starts, nb_arr, len_arr, shortm);
    k_pool    <<<BL / 4, 256, 0, stream>>>(hidden, starts, nb_arr, len_arr, pooled, scal);
}

// Round 9
// 177.541 us; speedup vs baseline: 1.1068x; 1.1068x over previous
//
#include <hip/hip_runtime.h>
#include <hip/hip_bf16.h>
#include <math.h>

#define L_SEQ 8192
#define B_BATCH 8
#define D_DIM 256
#define BL (B_BATCH * L_SEQ)
#define EPS_F 1.1920929e-07f

typedef __attribute__((ext_vector_type(8))) short short8;
typedef __attribute__((ext_vector_type(4))) float f32x4;
typedef __attribute__((ext_vector_type(4))) unsigned short u16x4;

// ws layout (bytes):
//   [0,       262144)  starts int32 BL (k_scan+)
//   [262144,  524288)  Bpack bf16: 2 segs (M1,M2) x 8 k8 x 16 ct fragments x 64 lanes x 8
//   [524288,  589824)  hard  uint8  BL
//   [589824,  589856)  n_b   int32  8
//   [589856,  589888)  len   int32  8

__device__ inline unsigned short f2bf(float x) {
    __hip_bfloat16 b = __float2bfloat16(x);
    return *(unsigned short*)&b;
}
__device__ inline float bf2f(unsigned short u) {
    __hip_bfloat16 b = *(__hip_bfloat16*)&u;
    return __bfloat162float(b);
}

// ------------------- K1: fused M = Wq^T*Wk - I  ->  bf16 hi/lo MFMA B-fragment pack
__global__ __launch_bounds__(256) void k_matMpack(
    const float* __restrict__ Wq, const float* __restrict__ Wk,
    unsigned short* __restrict__ Bpack) {
    __shared__ float Aq[64][33];
    __shared__ float Ak[64][17];
    const int f   = blockIdx.x;       // 0..127
    const int k8  = f >> 4, ct = f & 15;
    const int tid = threadIdx.x;
    const int n   = tid & 15;         // col within ct tile
    const int k   = tid >> 4;         // 0..15; thread owns rows k and k+16 of the strip
    float a0 = 0.f, a1 = 0.f;
    for (int e0 = 0; e0 < 256; e0 += 64) {
        for (int i = tid; i < 64 * 32; i += 256) {
            const int e = i >> 5, d = i & 31;
            Aq[e][d] = Wq[(e0 + e) * 256 + k8 * 32 + d];
        }
        for (int i = tid; i < 64 * 16; i += 256) {
            const int e = i >> 4, d = i & 15;
            Ak[e][d] = Wk[(e0 + e) * 256 + ct * 16 + d];
        }
        __syncthreads();
#pragma unroll 8
        for (int e = 0; e < 64; ++e) {
            a0 += Aq[e][k] * Ak[e][n];
            a1 += Aq[e][k + 16] * Ak[e][n];
        }
        __syncthreads();
    }
    const int col = ct * 16 + n;
    const float M0 = a0 - ((k8 * 32 + k)      == col ? 1.0f : 0.0f);
    const float M1 = a1 - ((k8 * 32 + k + 16) == col ? 1.0f : 0.0f);
    const unsigned short h0 = f2bf(M0), h1 = f2bf(M1);
    const unsigned short l0 = f2bf(M0 - bf2f(h0)), l1 = f2bf(M1 - bf2f(h1));
    unsigned short* dstH = Bpack + (size_t)(k8 * 16 + ct) * 512;
    unsigned short* dstL = dstH + 128 * 512;
    const int q0 = k >> 3, j0 = k & 7;
    const int q1 = (k + 16) >> 3;
    dstH[(q0 * 16 + n) * 8 + j0] = h0;
    dstH[(q1 * 16 + n) * 8 + j0] = h1;
    dstL[(q0 * 16 + n) * 8 + j0] = l0;
    dstL[(q1 * 16 + n) * 8 + j0] = l1;
}

// ------------------------------ K2: normalize + MFMA correction GEMM + cos + hard bit
// v9 = v7 structure (fused normalize; no global hi/lo round-trip — v8's 256 MiB
// round-trip cost more than its chain savings) + ILP-restructured staging:
// rows processed in 3 groups of 3, so the ss-reduce shfl chains, pd-dot chains,
// and convert streams interleave (3x shallower serial depth). Group g+1 loads
// issue before group g's reduce. B preload trimmed to 1 strip during staging
// (VGPR peak); bB/bC load right after the barrier.
#define RS 264   // LDS row stride in bf16 elems: 528 B
#define MM(A,Bv,C) __builtin_amdgcn_mfma_f32_16x16x32_bf16((A),(Bv),(C),0,0,0)
#define MFMA8(V0,V1,BN) \
    acc[0][0]=MM(V0,BN##_0,acc[0][0]); acc[0][1]=MM(V0,BN##_1,acc[0][1]); \
    acc[0][2]=MM(V0,BN##_2,acc[0][2]); acc[0][3]=MM(V0,BN##_3,acc[0][3]); \
    acc[1][0]=MM(V1,BN##_0,acc[1][0]); acc[1][1]=MM(V1,BN##_1,acc[1][1]); \
    acc[1][2]=MM(V1,BN##_2,acc[1][2]); acc[1][3]=MM(V1,BN##_3,acc[1][3]);
#define LOADB(BN,S) \
    BN##_0 = Bld[(((S) * 16) + wc4 + 0) * 64]; \
    BN##_1 = Bld[(((S) * 16) + wc4 + 1) * 64]; \
    BN##_2 = Bld[(((S) * 16) + wc4 + 2) * 64]; \
    BN##_3 = Bld[(((S) * 16) + wc4 + 3) * 64];
#define STRIP_HL(S,BN) { \
    const int co = ((S) & 7) * 32; \
    const short8 hv0 = *(const short8*)(hA0 + co), hv1 = *(const short8*)(hA1 + co); \
    const short8 lv0 = *(const short8*)(lA0 + co), lv1 = *(const short8*)(lA1 + co); \
    MFMA8(hv0, hv1, BN); \
    MFMA8(lv0, lv1, BN); \
    LOADB(BN, (S) + 3); }
#define STRIP_H(S,BN) { \
    const int co = ((S) & 7) * 32; \
    const short8 hv0 = *(const short8*)(hA0 + co), hv1 = *(const short8*)(hA1 + co); \
    MFMA8(hv0, hv1, BN); \
    if ((S) + 3 < 16) { LOADB(BN, (S) + 3); } }
#define DOT4(a,b) ((a).x*(b).x + (a).y*(b).y + (a).z*(b).z + (a).w*(b).w)

__global__ __launch_bounds__(256, 2) void k_cosmfma(
    const float* __restrict__ hidden, const unsigned short* __restrict__ Bpack,
    const float* __restrict__ noise, unsigned char* __restrict__ hard) {
    __shared__ __attribute__((aligned(16))) unsigned short hiA[33 * RS]; // 17,424 B
    __shared__ __attribute__((aligned(16))) unsigned short loA[33 * RS]; // 17,424 B
    __shared__ float Vpart[4][32];                                       //    512 B
    __shared__ float dots[32];                                           //    128 B

    const int tid  = threadIdx.x;
    const int lane = tid & 63;
    const int w    = tid >> 6;        // wave 0..3
    const int wc4  = w * 4;           // ct base: cols [w*64, w*64+64)
    const int T0   = blockIdx.x * 32;

    const short8* __restrict__ Bld = (const short8*)Bpack + lane;

    // 1-strip B preload (flies during staging; keeps staging VGPR peak low)
    short8 bA_0, bA_1, bA_2, bA_3, bB_0, bB_1, bB_2, bB_3, bC_0, bC_1, bC_2, bC_3;
    LOADB(bA, 0);

    // ---- stage rows [w*8, w*8+8]: ILP groups of 3 rows ----
    // Row i (slab) <-> token T0-1+i (clamped at 0). dots[i-1] = hn_i . hn_{i-1}.
    {
        const int r0 = w * 8;
        const float4* __restrict__ H4 = (const float4*)hidden;
        float4 vg0, vg1, vg2, vn0, vn1, vn2;
        {
            int tokA = T0 - 1 + r0; if (tokA < 0) tokA = 0;
            vg0 = H4[(size_t)tokA * 64 + lane];
            vg1 = H4[(size_t)(T0 + r0) * 64 + lane];          // row r0+1
            vg2 = H4[(size_t)(T0 + r0 + 1) * 64 + lane];      // row r0+2
        }
        float4 hp = {0.f, 0.f, 0.f, 0.f};
#pragma unroll
        for (int g = 0; g < 3; ++g) {
            if (g < 2) {   // prefetch rows r0+3g+3..5 = tokens T0+r0+3g+2..4
                vn0 = H4[(size_t)(T0 + r0 + 3 * g + 2) * 64 + lane];
                vn1 = H4[(size_t)(T0 + r0 + 3 * g + 3) * 64 + lane];
                vn2 = H4[(size_t)(T0 + r0 + 3 * g + 4) * 64 + lane];
            }
            // 3 interleaved 64-lane sum-of-squares reductions
            float s0 = DOT4(vg0, vg0), s1 = DOT4(vg1, vg1), s2 = DOT4(vg2, vg2);
#pragma unroll
            for (int sh = 32; sh >= 1; sh >>= 1) {
                s0 += __shfl_xor(s0, sh);
                s1 += __shfl_xor(s1, sh);
                s2 += __shfl_xor(s2, sh);
            }
            const float i0 = 1.0f / fmaxf(sqrtf(s0), 1e-12f);
            const float i1 = 1.0f / fmaxf(sqrtf(s1), 1e-12f);
            const float i2 = 1.0f / fmaxf(sqrtf(s2), 1e-12f);
            float4 h0, h1, h2;
            h0.x = vg0.x * i0; h0.y = vg0.y * i0; h0.z = vg0.z * i0; h0.w = vg0.w * i0;
            h1.x = vg1.x * i1; h1.y = vg1.y * i1; h1.z = vg1.z * i1; h1.w = vg1.w * i1;
            h2.x = vg2.x * i2; h2.y = vg2.y * i2; h2.z = vg2.z * i2; h2.w = vg2.w * i2;
            // convert + LDS writes (rows r0+3g+0..2)
            {
                const int ib = (r0 + 3 * g) * RS + lane * 4;
                const unsigned short ax = f2bf(h0.x), ay = f2bf(h0.y),
                                     az = f2bf(h0.z), aw = f2bf(h0.w);
                const u16x4 ha = {ax, ay, az, aw};
                const u16x4 la = {f2bf(h0.x - bf2f(ax)), f2bf(h0.y - bf2f(ay)),
                                  f2bf(h0.z - bf2f(az)), f2bf(h0.w - bf2f(aw))};
                *(u16x4*)&hiA[ib] = ha;  *(u16x4*)&loA[ib] = la;
                const unsigned short bx = f2bf(h1.x), by = f2bf(h1.y),
                                     bz = f2bf(h1.z), bw = f2bf(h1.w);
                const u16x4 hb = {bx, by, bz, bw};
                const u16x4 lb = {f2bf(h1.x - bf2f(bx)), f2bf(h1.y - bf2f(by)),
                                  f2bf(h1.z - bf2f(bz)), f2bf(h1.w - bf2f(bw))};
                *(u16x4*)&hiA[ib + RS] = hb;  *(u16x4*)&loA[ib + RS] = lb;
                const unsigned short cx = f2bf(h2.x), cy = f2bf(h2.y),
                                     cz = f2bf(h2.z), cw = f2bf(h2.w);
                const u16x4 hc = {cx, cy, cz, cw};
                const u16x4 lc = {f2bf(h2.x - bf2f(cx)), f2bf(h2.y - bf2f(cy)),
                                  f2bf(h2.z - bf2f(cz)), f2bf(h2.w - bf2f(cw))};
                *(u16x4*)&hiA[ib + 2 * RS] = hc;  *(u16x4*)&loA[ib + 2 * RS] = lc;
            }
            // pair dots: pd(i) = h_i . h_{i-1} -> dots[i-1]; skip i = r0 (g==0,j==0)
            float p0 = DOT4(hp, h0), p1 = DOT4(h0, h1), p2 = DOT4(h1, h2);
#pragma unroll
            for (int sh = 32; sh >= 1; sh >>= 1) {
                p0 += __shfl_xor(p0, sh);
                p1 += __shfl_xor(p1, sh);
                p2 += __shfl_xor(p2, sh);
            }
            if (lane == 0) {
                const int i0r = r0 + 3 * g;
                if (g > 0) dots[i0r - 1] = p0;
                dots[i0r]     = p1;
                dots[i0r + 1] = p2;
            }
            hp = h2;
            vg0 = vn0; vg1 = vn1; vg2 = vn2;
        }
    }
    __syncthreads();   // waves read other waves' slab rows below

    // fill the rest of the B pipeline (strips 1,2) — first use ~1 strip away
    LOADB(bB, 1);
    LOADB(bC, 2);

    // A-frag pointers: frag af covers slab rows af*16 + m; lane holds A[m][q*8+j]
    const int m = lane & 15, q = lane >> 4;
    const unsigned short* __restrict__ hA0 = &hiA[( 0 + m) * RS + q * 8];
    const unsigned short* __restrict__ hA1 = &hiA[(16 + m) * RS + q * 8];
    const unsigned short* __restrict__ lA0 = &loA[( 0 + m) * RS + q * 8];
    const unsigned short* __restrict__ lA1 = &loA[(16 + m) * RS + q * 8];

    f32x4 acc[2][4];
#pragma unroll
    for (int af = 0; af < 2; ++af)
#pragma unroll
        for (int c = 0; c < 4; ++c) { f32x4 z = {0.f, 0.f, 0.f, 0.f}; acc[af][c] = z; }

    // strips 0..7: seg0 (hi B; A h+l); strips 8..15: seg1 (lo B; A h only)
    STRIP_HL(0, bA)  STRIP_HL(1, bB)  STRIP_HL(2, bC)  STRIP_HL(3, bA)
    STRIP_HL(4, bB)  STRIP_HL(5, bC)  STRIP_HL(6, bA)  STRIP_HL(7, bB)
    STRIP_H (8, bC)  STRIP_H (9, bA)  STRIP_H (10, bB) STRIP_H (11, bC)
    STRIP_H (12, bA) STRIP_H (13, bB) STRIP_H (14, bC) STRIP_H (15, bA)

    // ---- epilogue: per-row partial over this wave's 64 cols, then cross-wave reduce ----
    // D row = af*16 + q*4 + r (token T0+row), D col = (wc4+c)*16 + m.
#pragma unroll
    for (int af = 0; af < 2; ++af) {
#pragma unroll
        for (int r = 0; r < 4; ++r) {
            const int row = af * 16 + (q << 2) + r;
            const int ib  = (row + 1) * RS + wc4 * 16 + m;
            float pp = acc[af][0][r] * (bf2f(hiA[ib     ]) + bf2f(loA[ib     ]))
                     + acc[af][1][r] * (bf2f(hiA[ib + 16]) + bf2f(loA[ib + 16]))
                     + acc[af][2][r] * (bf2f(hiA[ib + 32]) + bf2f(loA[ib + 32]))
                     + acc[af][3][r] * (bf2f(hiA[ib + 48]) + bf2f(loA[ib + 48]));
            pp += __shfl_xor(pp, 1);
            pp += __shfl_xor(pp, 2);
            pp += __shfl_xor(pp, 4);
            pp += __shfl_xor(pp, 8);
            if (m == 0) Vpart[w][row] = pp;
        }
    }
    __syncthreads();
    if (tid < 32) {
        const int rl = tid;             // token t = T0 + rl
        const float part = Vpart[0][rl] + Vpart[1][rl] + Vpart[2][rl] + Vpart[3][rl];
        const int t = T0 + rl;
        const int l = t & (L_SEQ - 1);
        float p;
        if (l == 0) {
            p = 1.0f;
        } else {
            p = (1.0f - (part + dots[rl])) * 0.5f;
            p = fminf(fmaxf(p, 0.0f), 1.0f);
        }
        p = fminf(fmaxf(p, EPS_F), 1.0f - EPS_F);
        float u = noise[t];
        u = fminf(fmaxf(u, EPS_F), 1.0f - EPS_F);
        const float z = ((logf(p) - log1pf(-p)) + logf(u)) - log1pf(-u);
        hard[t] = (z > 0.0f) ? (unsigned char)1 : (unsigned char)0;
    }
}

// ---------------------- K3: per-row length, forced boundary, scan -> starts, n_b, mask
__global__ __launch_bounds__(1024) void k_scan(
    const float* __restrict__ mask, const unsigned char* __restrict__ hard,
    int* __restrict__ starts, int* __restrict__ nb_arr,
    int* __restrict__ len_arr, float* __restrict__ out_short) {
    __shared__ int wsum[16];
    __shared__ int s_len;
    const int b = blockIdx.x, tid = threadIdx.x;
    const int lane = tid & 63, wv = tid >> 6;   // 16 waves
    const int base = b * L_SEQ;

    // row length = sum(mask): 8 floats per thread
    const float4* m4 = (const float4*)(mask + base);
    const float4 va = m4[tid * 2], vb = m4[tid * 2 + 1];
    int cnt = (va.x != 0.f) + (va.y != 0.f) + (va.z != 0.f) + (va.w != 0.f)
            + (vb.x != 0.f) + (vb.y != 0.f) + (vb.z != 0.f) + (vb.w != 0.f);
#pragma unroll
    for (int sh = 32; sh >= 1; sh >>= 1) cnt += __shfl_xor(cnt, sh);
    if (lane == 0) wsum[wv] = cnt;
    __syncthreads();
    if (tid == 0) {
        int s = 0;
        for (int i = 0; i < 16; ++i) s += wsum[i];
        s_len = s;
    }
    __syncthreads();
    const int len = s_len;

    // adjusted hard bits for this thread's 8 tokens [8*tid, 8*tid+8)
    const int i0 = tid * 8;
    const uint2 hb = ((const uint2*)(hard + base))[tid];
    int c = 0;
    unsigned int bits = 0;
#pragma unroll
    for (int j = 0; j < 8; ++j) {
        const unsigned int byte = ((j < 4 ? hb.x : hb.y) >> (8 * (j & 3))) & 0xffu;
        int h = ((i0 + j) < len) ? (int)(byte != 0u) : 0;
        if (len < L_SEQ && (i0 + j) == len - 1) h = 1;  // forced boundary at last real token
        bits |= (unsigned int)h << j;
        c += h;
    }
    // inclusive wave scan of counts
    int x = c;
#pragma unroll
    for (int ofs = 1; ofs < 64; ofs <<= 1) {
        const int t = __shfl_up(x, ofs);
        if (lane >= ofs) x += t;
    }
    if (lane == 63) wsum[wv] = x;
    __syncthreads();
    int woff = 0, nb = 0;
#pragma unroll
    for (int i = 0; i < 16; ++i) {
        const int t = wsum[i];
        nb += t;
        if (i < wv) woff += t;
    }
    int run = woff + x - c;   // exclusive prefix for this thread
#pragma unroll
    for (int j = 0; j < 8; ++j)
        if ((bits >> j) & 1u) { starts[base + run] = i0 + j; ++run; }

    if (tid == 0) { nb_arr[b] = nb; len_arr[b] = len; }

    float4 o0, o1;
    o0.x = (i0 + 0) < nb ? 1.f : 0.f; o0.y = (i0 + 1) < nb ? 1.f : 0.f;
    o0.z = (i0 + 2) < nb ? 1.f : 0.f; o0.w = (i0 + 3) < nb ? 1.f : 0.f;
    o1.x = (i0 + 4) < nb ? 1.f : 0.f; o1.y = (i0 + 5) < nb ? 1.f : 0.f;
    o1.z = (i0 + 6) < nb ? 1.f : 0.f; o1.w = (i0 + 7) < nb ? 1.f : 0.f;
    float4* os4 = (float4*)(out_short + base);
    os4[tid * 2] = o0;
    os4[tid * 2 + 1] = o1;
}

// ------------------- K4: one wave per segment, mean-pool (+ fused scalars/loss)
__global__ __launch_bounds__(256) void k_pool(
    const float* __restrict__ hidden, const int* __restrict__ starts,
    const int* __restrict__ nb_arr, const int* __restrict__ len_arr,
    float* __restrict__ pooled, float* __restrict__ out_scal) {
    const int tid  = threadIdx.x;
    const int lane = tid & 63;
    const int wid  = blockIdx.x * 4 + (tid >> 6);
    const int b    = wid >> 13;       // / 8192
    const int s    = wid & (L_SEQ - 1);
    const int nb   = nb_arr[b];

    if (blockIdx.x == 0 && tid == 0) {   // fused k_final (nb/len ready from k_scan)
        int nbt = 0, ln = 0;
        for (int i = 0; i < B_BATCH; ++i) { nbt += nb_arr[i]; ln += len_arr[i]; }
        const double k = (double)nbt, n = (double)ln;
        const double logp = lgamma(n + 1.0) - lgamma(k + 1.0) - lgamma(n - k + 1.0)
                            + k * log(0.2) + (n - k) * log(0.8);
        out_scal[0] = (float)(-logp / n);
        out_scal[1] = (float)nbt;
        out_scal[2] = (float)ln;
    }

    float4 res = {0.f, 0.f, 0.f, 0.f};
    if (s < nb) {
        const int start = (s == 0) ? 0 : starts[b * L_SEQ + s];
        const int end   = (s + 1 < nb) ? starts[b * L_SEQ + s + 1] : len_arr[b];
        float4 acc = {0.f, 0.f, 0.f, 0.f};
        for (int t = start; t < end; ++t) {
            const float4 v = ((const float4*)hidden)[(b * L_SEQ + t) * 64 + lane];
            acc.x += v.x; acc.y += v.y; acc.z += v.z; acc.w += v.w;
        }
        const float cntf = (float)(end - start);
        res.x = acc.x / cntf; res.y = acc.y / cntf; res.z = acc.z / cntf; res.w = acc.w / cntf;
    }
    ((float4*)pooled)[(size_t)wid * 64 + lane] = res;
}

extern "C" void kernel_launch(void* const* d_in, const int* in_sizes, int n_in,
                              void* d_out, int out_size, void* d_ws, size_t ws_size,
                              hipStream_t stream) {
    const float* hidden = (const float*)d_in[0];
    const float* Wq     = (const float*)d_in[1];
    const float* Wk     = (const float*)d_in[2];
    const float* noise  = (const float*)d_in[3];
    const float* mask   = (const float*)d_in[4];
    float* out = (float*)d_out;
    char* ws = (char*)d_ws;

    int*            starts = (int*)(ws);
    unsigned short* Bpack  = (unsigned short*)(ws + 262144);
    unsigned char*  hard   = (unsigned char*)(ws + 524288);
    int*            nb_arr = (int*)(ws + 589824);
    int*            len_arr= (int*)(ws + 589856);

    float* pooled = out;
    float* scal   = out + (size_t)BL * D_DIM;
    float* shortm = scal + 3;

    k_matMpack<<<128, 256, 0, stream>>>(Wq, Wk, Bpack);
    k_cosmfma <<<BL / 32, 256, 0, stream>>>(hidden, Bpack, noise, hard);
    k_scan    <<<B_BATCH, 1024, 0, stream>>>(mask, hard, starts, nb_arr, len_arr, shortm);
    k_pool    <<<BL / 4, 256, 0, stream>>>(hidden, starts, nb_arr, len_arr, pooled, scal);
}

// Round 10
// 166.148 us; speedup vs baseline: 1.1827x; 1.0686x over previous
//
#include <hip/hip_runtime.h>
#include <hip/hip_bf16.h>
#include <math.h>

#define L_SEQ 8192
#define B_BATCH 8
#define D_DIM 256
#define BL (B_BATCH * L_SEQ)
#define EPS_F 1.1920929e-07f

typedef __attribute__((ext_vector_type(8))) short short8;
typedef __attribute__((ext_vector_type(4))) float f32x4;
typedef __attribute__((ext_vector_type(4))) unsigned short u16x4;

// ws layout (bytes):
//   [0,       262144)  starts int32 BL (k_scan+)
//   [262144,  524288)  Bpack bf16: 2 segs (M1,M2) x 8 k8 x 16 ct fragments x 64 lanes x 8
//   [524288,  589824)  hard  uint8  BL
//   [589824,  589856)  n_b   int32  8
//   [589856,  589888)  len   int32  8

__device__ inline unsigned short f2bf(float x) {
    __hip_bfloat16 b = __float2bfloat16(x);
    return *(unsigned short*)&b;
}
__device__ inline float bf2f(unsigned short u) {
    __hip_bfloat16 b = *(__hip_bfloat16*)&u;
    return __bfloat162float(b);
}

// ------------------- K1: fused M = Wq^T*Wk - I  ->  bf16 hi/lo MFMA B-fragment pack
// v10: 256 blocks (16x16 tile each, 1 output/thread) — v9's 128 blocks left half
// the CUs idle on this small GEMM (~10 us). Same math, 2x parallel.
__global__ __launch_bounds__(256) void k_matMpack(
    const float* __restrict__ Wq, const float* __restrict__ Wk,
    unsigned short* __restrict__ Bpack) {
    __shared__ float Aq[64][17];
    __shared__ float Ak[64][17];
    const int f   = blockIdx.x;       // 0..255
    const int rt  = f >> 4;           // row tile: M rows [rt*16, rt*16+16)
    const int ct  = f & 15;           // col tile: M cols [ct*16, ct*16+16)
    const int tid = threadIdx.x;
    const int n   = tid & 15;         // col within tile
    const int k   = tid >> 4;         // row within tile
    float a = 0.f;
    for (int e0 = 0; e0 < 256; e0 += 64) {
        for (int i = tid; i < 64 * 16; i += 256) {
            const int e = i >> 4, d = i & 15;
            Aq[e][d] = Wq[(e0 + e) * 256 + rt * 16 + d];
            Ak[e][d] = Wk[(e0 + e) * 256 + ct * 16 + d];
        }
        __syncthreads();
#pragma unroll 16
        for (int e = 0; e < 64; ++e) a += Aq[e][k] * Ak[e][n];
        __syncthreads();
    }
    const int row = rt * 16 + k, col = ct * 16 + n;
    const float Mv = a - (row == col ? 1.0f : 0.0f);
    const unsigned short h = f2bf(Mv);
    const unsigned short l = f2bf(Mv - bf2f(h));
    // B-frag layout: frag (k8*16+ct), lane q*16+n holds B[k8*32+q*8+j][ct*16+n]
    const int k8 = row >> 5, rq = (row & 31) >> 3, j = row & 7;
    unsigned short* dstH = Bpack + (size_t)(k8 * 16 + ct) * 512 + (rq * 16 + n) * 8 + j;
    dstH[0] = h;
    dstH[128 * 512] = l;
}

// ------------------------------ K2: normalize + MFMA correction GEMM + cos + hard bit
// v10 = v9 (fused ILP-3 staging, 32-tok tiles, col-split, 4 blk/CU) +
//  - 4-deep B register pipeline (bA..bD): prefetch distance 2 -> 3 strips (~300+ cy)
//    to cover L2-under-load latency on the shared Bpack reads.
//  - s_setprio(1) around MFMA clusters (waves are barrier-free + phase-staggered in
//    the strip loop — the regime where setprio measured +4-7%).
#define RS 264   // LDS row stride in bf16 elems: 528 B
#define MM(A,Bv,C) __builtin_amdgcn_mfma_f32_16x16x32_bf16((A),(Bv),(C),0,0,0)
#define MFMA8(V0,V1,BN) \
    acc[0][0]=MM(V0,BN##_0,acc[0][0]); acc[0][1]=MM(V0,BN##_1,acc[0][1]); \
    acc[0][2]=MM(V0,BN##_2,acc[0][2]); acc[0][3]=MM(V0,BN##_3,acc[0][3]); \
    acc[1][0]=MM(V1,BN##_0,acc[1][0]); acc[1][1]=MM(V1,BN##_1,acc[1][1]); \
    acc[1][2]=MM(V1,BN##_2,acc[1][2]); acc[1][3]=MM(V1,BN##_3,acc[1][3]);
#define LOADB(BN,S) \
    BN##_0 = Bld[(((S) * 16) + wc4 + 0) * 64]; \
    BN##_1 = Bld[(((S) * 16) + wc4 + 1) * 64]; \
    BN##_2 = Bld[(((S) * 16) + wc4 + 2) * 64]; \
    BN##_3 = Bld[(((S) * 16) + wc4 + 3) * 64];
#define STRIP_HL(S,BN) { \
    const int co = ((S) & 7) * 32; \
    const short8 hv0 = *(const short8*)(hA0 + co), hv1 = *(const short8*)(hA1 + co); \
    const short8 lv0 = *(const short8*)(lA0 + co), lv1 = *(const short8*)(lA1 + co); \
    __builtin_amdgcn_s_setprio(1); \
    MFMA8(hv0, hv1, BN); \
    MFMA8(lv0, lv1, BN); \
    __builtin_amdgcn_s_setprio(0); \
    if ((S) + 4 < 16) { LOADB(BN, (S) + 4); } }
#define STRIP_H(S,BN) { \
    const int co = ((S) & 7) * 32; \
    const short8 hv0 = *(const short8*)(hA0 + co), hv1 = *(const short8*)(hA1 + co); \
    __builtin_amdgcn_s_setprio(1); \
    MFMA8(hv0, hv1, BN); \
    __builtin_amdgcn_s_setprio(0); \
    if ((S) + 4 < 16) { LOADB(BN, (S) + 4); } }
#define DOT4(a,b) ((a).x*(b).x + (a).y*(b).y + (a).z*(b).z + (a).w*(b).w)

__global__ __launch_bounds__(256, 2) void k_cosmfma(
    const float* __restrict__ hidden, const unsigned short* __restrict__ Bpack,
    const float* __restrict__ noise, unsigned char* __restrict__ hard) {
    __shared__ __attribute__((aligned(16))) unsigned short hiA[33 * RS]; // 17,424 B
    __shared__ __attribute__((aligned(16))) unsigned short loA[33 * RS]; // 17,424 B
    __shared__ float Vpart[4][32];                                       //    512 B
    __shared__ float dots[32];                                           //    128 B

    const int tid  = threadIdx.x;
    const int lane = tid & 63;
    const int w    = tid >> 6;        // wave 0..3
    const int wc4  = w * 4;           // ct base: cols [w*64, w*64+64)
    const int T0   = blockIdx.x * 32;

    const short8* __restrict__ Bld = (const short8*)Bpack + lane;

    // 1-strip B preload (flies during staging; keeps staging VGPR peak low)
    short8 bA_0, bA_1, bA_2, bA_3, bB_0, bB_1, bB_2, bB_3,
           bC_0, bC_1, bC_2, bC_3, bD_0, bD_1, bD_2, bD_3;
    LOADB(bA, 0);

    // ---- stage rows [w*8, w*8+8]: ILP groups of 3 rows ----
    // Row i (slab) <-> token T0-1+i (clamped at 0). dots[i-1] = hn_i . hn_{i-1}.
    {
        const int r0 = w * 8;
        const float4* __restrict__ H4 = (const float4*)hidden;
        float4 vg0, vg1, vg2, vn0, vn1, vn2;
        {
            int tokA = T0 - 1 + r0; if (tokA < 0) tokA = 0;
            vg0 = H4[(size_t)tokA * 64 + lane];
            vg1 = H4[(size_t)(T0 + r0) * 64 + lane];          // row r0+1
            vg2 = H4[(size_t)(T0 + r0 + 1) * 64 + lane];      // row r0+2
        }
        float4 hp = {0.f, 0.f, 0.f, 0.f};
#pragma unroll
        for (int g = 0; g < 3; ++g) {
            if (g < 2) {   // prefetch rows r0+3g+3..5 = tokens T0+r0+3g+2..4
                vn0 = H4[(size_t)(T0 + r0 + 3 * g + 2) * 64 + lane];
                vn1 = H4[(size_t)(T0 + r0 + 3 * g + 3) * 64 + lane];
                vn2 = H4[(size_t)(T0 + r0 + 3 * g + 4) * 64 + lane];
            }
            // 3 interleaved 64-lane sum-of-squares reductions
            float s0 = DOT4(vg0, vg0), s1 = DOT4(vg1, vg1), s2 = DOT4(vg2, vg2);
#pragma unroll
            for (int sh = 32; sh >= 1; sh >>= 1) {
                s0 += __shfl_xor(s0, sh);
                s1 += __shfl_xor(s1, sh);
                s2 += __shfl_xor(s2, sh);
            }
            const float i0 = 1.0f / fmaxf(sqrtf(s0), 1e-12f);
            const float i1 = 1.0f / fmaxf(sqrtf(s1), 1e-12f);
            const float i2 = 1.0f / fmaxf(sqrtf(s2), 1e-12f);
            float4 h0, h1, h2;
            h0.x = vg0.x * i0; h0.y = vg0.y * i0; h0.z = vg0.z * i0; h0.w = vg0.w * i0;
            h1.x = vg1.x * i1; h1.y = vg1.y * i1; h1.z = vg1.z * i1; h1.w = vg1.w * i1;
            h2.x = vg2.x * i2; h2.y = vg2.y * i2; h2.z = vg2.z * i2; h2.w = vg2.w * i2;
            // convert + LDS writes (rows r0+3g+0..2)
            {
                const int ib = (r0 + 3 * g) * RS + lane * 4;
                const unsigned short ax = f2bf(h0.x), ay = f2bf(h0.y),
                                     az = f2bf(h0.z), aw = f2bf(h0.w);
                const u16x4 ha = {ax, ay, az, aw};
                const u16x4 la = {f2bf(h0.x - bf2f(ax)), f2bf(h0.y - bf2f(ay)),
                                  f2bf(h0.z - bf2f(az)), f2bf(h0.w - bf2f(aw))};
                *(u16x4*)&hiA[ib] = ha;  *(u16x4*)&loA[ib] = la;
                const unsigned short bx = f2bf(h1.x), by = f2bf(h1.y),
                                     bz = f2bf(h1.z), bw = f2bf(h1.w);
                const u16x4 hb = {bx, by, bz, bw};
                const u16x4 lb = {f2bf(h1.x - bf2f(bx)), f2bf(h1.y - bf2f(by)),
                                  f2bf(h1.z - bf2f(bz)), f2bf(h1.w - bf2f(bw))};
                *(u16x4*)&hiA[ib + RS] = hb;  *(u16x4*)&loA[ib + RS] = lb;
                const unsigned short cx = f2bf(h2.x), cy = f2bf(h2.y),
                                     cz = f2bf(h2.z), cw = f2bf(h2.w);
                const u16x4 hc = {cx, cy, cz, cw};
                const u16x4 lc = {f2bf(h2.x - bf2f(cx)), f2bf(h2.y - bf2f(cy)),
                                  f2bf(h2.z - bf2f(cz)), f2bf(h2.w - bf2f(cw))};
                *(u16x4*)&hiA[ib + 2 * RS] = hc;  *(u16x4*)&loA[ib + 2 * RS] = lc;
            }
            // pair dots: pd(i) = h_i . h_{i-1} -> dots[i-1]; skip i = r0 (g==0,j==0)
            float p0 = DOT4(hp, h0), p1 = DOT4(h0, h1), p2 = DOT4(h1, h2);
#pragma unroll
            for (int sh = 32; sh >= 1; sh >>= 1) {
                p0 += __shfl_xor(p0, sh);
                p1 += __shfl_xor(p1, sh);
                p2 += __shfl_xor(p2, sh);
            }
            if (lane == 0) {
                const int i0r = r0 + 3 * g;
                if (g > 0) dots[i0r - 1] = p0;
                dots[i0r]     = p1;
                dots[i0r + 1] = p2;
            }
            hp = h2;
            vg0 = vn0; vg1 = vn1; vg2 = vn2;
        }
    }
    __syncthreads();   // waves read other waves' slab rows below

    // fill the rest of the B pipeline (strips 1..3)
    LOADB(bB, 1);
    LOADB(bC, 2);
    LOADB(bD, 3);

    // A-frag pointers: frag af covers slab rows af*16 + m; lane holds A[m][q*8+j]
    const int m = lane & 15, q = lane >> 4;
    const unsigned short* __restrict__ hA0 = &hiA[( 0 + m) * RS + q * 8];
    const unsigned short* __restrict__ hA1 = &hiA[(16 + m) * RS + q * 8];
    const unsigned short* __restrict__ lA0 = &loA[( 0 + m) * RS + q * 8];
    const unsigned short* __restrict__ lA1 = &loA[(16 + m) * RS + q * 8];

    f32x4 acc[2][4];
#pragma unroll
    for (int af = 0; af < 2; ++af)
#pragma unroll
        for (int c = 0; c < 4; ++c) { f32x4 z = {0.f, 0.f, 0.f, 0.f}; acc[af][c] = z; }

    // strips 0..7: seg0 (hi B; A h+l); strips 8..15: seg1 (lo B; A h only)
    STRIP_HL(0, bA)  STRIP_HL(1, bB)  STRIP_HL(2, bC)  STRIP_HL(3, bD)
    STRIP_HL(4, bA)  STRIP_HL(5, bB)  STRIP_HL(6, bC)  STRIP_HL(7, bD)
    STRIP_H (8, bA)  STRIP_H (9, bB)  STRIP_H (10, bC) STRIP_H (11, bD)
    STRIP_H (12, bA) STRIP_H (13, bB) STRIP_H (14, bC) STRIP_H (15, bD)

    // ---- epilogue: per-row partial over this wave's 64 cols, then cross-wave reduce ----
    // D row = af*16 + q*4 + r (token T0+row), D col = (wc4+c)*16 + m.
#pragma unroll
    for (int af = 0; af < 2; ++af) {
#pragma unroll
        for (int r = 0; r < 4; ++r) {
            const int row = af * 16 + (q << 2) + r;
            const int ib  = (row + 1) * RS + wc4 * 16 + m;
            float pp = acc[af][0][r] * (bf2f(hiA[ib     ]) + bf2f(loA[ib     ]))
                     + acc[af][1][r] * (bf2f(hiA[ib + 16]) + bf2f(loA[ib + 16]))
                     + acc[af][2][r] * (bf2f(hiA[ib + 32]) + bf2f(loA[ib + 32]))
                     + acc[af][3][r] * (bf2f(hiA[ib + 48]) + bf2f(loA[ib + 48]));
            pp += __shfl_xor(pp, 1);
            pp += __shfl_xor(pp, 2);
            pp += __shfl_xor(pp, 4);
            pp += __shfl_xor(pp, 8);
            if (m == 0) Vpart[w][row] = pp;
        }
    }
    __syncthreads();
    if (tid < 32) {
        const int rl = tid;             // token t = T0 + rl
        const float part = Vpart[0][rl] + Vpart[1][rl] + Vpart[2][rl] + Vpart[3][rl];
        const int t = T0 + rl;
        const int l = t & (L_SEQ - 1);
        float p;
        if (l == 0) {
            p = 1.0f;
        } else {
            p = (1.0f - (part + dots[rl])) * 0.5f;
            p = fminf(fmaxf(p, 0.0f), 1.0f);
        }
        p = fminf(fmaxf(p, EPS_F), 1.0f - EPS_F);
        float u = noise[t];
        u = fminf(fmaxf(u, EPS_F), 1.0f - EPS_F);
        const float z = ((logf(p) - log1pf(-p)) + logf(u)) - log1pf(-u);
        hard[t] = (z > 0.0f) ? (unsigned char)1 : (unsigned char)0;
    }
}

// ---------------------- K3: per-row length, forced boundary, scan -> starts, n_b, mask
__global__ __launch_bounds__(1024) void k_scan(
    const float* __restrict__ mask, const unsigned char* __restrict__ hard,
    int* __restrict__ starts, int* __restrict__ nb_arr,
    int* __restrict__ len_arr, float* __restrict__ out_short) {
    __shared__ int wsum[16];
    __shared__ int s_len;
    const int b = blockIdx.x, tid = threadIdx.x;
    const int lane = tid & 63, wv = tid >> 6;   // 16 waves
    const int base = b * L_SEQ;

    // row length = sum(mask): 8 floats per thread
    const float4* m4 = (const float4*)(mask + base);
    const float4 va = m4[tid * 2], vb = m4[tid * 2 + 1];
    int cnt = (va.x != 0.f) + (va.y != 0.f) + (va.z != 0.f) + (va.w != 0.f)
            + (vb.x != 0.f) + (vb.y != 0.f) + (vb.z != 0.f) + (vb.w != 0.f);
#pragma unroll
    for (int sh = 32; sh >= 1; sh >>= 1) cnt += __shfl_xor(cnt, sh);
    if (lane == 0) wsum[wv] = cnt;
    __syncthreads();
    if (tid == 0) {
        int s = 0;
        for (int i = 0; i < 16; ++i) s += wsum[i];
        s_len = s;
    }
    __syncthreads();
    const int len = s_len;

    // adjusted hard bits for this thread's 8 tokens [8*tid, 8*tid+8)
    const int i0 = tid * 8;
    const uint2 hb = ((const uint2*)(hard + base))[tid];
    int c = 0;
    unsigned int bits = 0;
#pragma unroll
    for (int j = 0; j < 8; ++j) {
        const unsigned int byte = ((j < 4 ? hb.x : hb.y) >> (8 * (j & 3))) & 0xffu;
        int h = ((i0 + j) < len) ? (int)(byte != 0u) : 0;
        if (len < L_SEQ && (i0 + j) == len - 1) h = 1;  // forced boundary at last real token
        bits |= (unsigned int)h << j;
        c += h;
    }
    // inclusive wave scan of counts
    int x = c;
#pragma unroll
    for (int ofs = 1; ofs < 64; ofs <<= 1) {
        const int t = __shfl_up(x, ofs);
        if (lane >= ofs) x += t;
    }
    if (lane == 63) wsum[wv] = x;
    __syncthreads();
    int woff = 0, nb = 0;
#pragma unroll
    for (int i = 0; i < 16; ++i) {
        const int t = wsum[i];
        nb += t;
        if (i < wv) woff += t;
    }
    int run = woff + x - c;   // exclusive prefix for this thread
#pragma unroll
    for (int j = 0; j < 8; ++j)
        if ((bits >> j) & 1u) { starts[base + run] = i0 + j; ++run; }

    if (tid == 0) { nb_arr[b] = nb; len_arr[b] = len; }

    float4 o0, o1;
    o0.x = (i0 + 0) < nb ? 1.f : 0.f; o0.y = (i0 + 1) < nb ? 1.f : 0.f;
    o0.z = (i0 + 2) < nb ? 1.f : 0.f; o0.w = (i0 + 3) < nb ? 1.f : 0.f;
    o1.x = (i0 + 4) < nb ? 1.f : 0.f; o1.y = (i0 + 5) < nb ? 1.f : 0.f;
    o1.z = (i0 + 6) < nb ? 1.f : 0.f; o1.w = (i0 + 7) < nb ? 1.f : 0.f;
    float4* os4 = (float4*)(out_short + base);
    os4[tid * 2] = o0;
    os4[tid * 2 + 1] = o1;
}

// ------------------- K4: one wave per segment, mean-pool (+ fused scalars/loss)
__global__ __launch_bounds__(256) void k_pool(
    const float* __restrict__ hidden, const int* __restrict__ starts,
    const int* __restrict__ nb_arr, const int* __restrict__ len_arr,
    float* __restrict__ pooled, float* __restrict__ out_scal) {
    const int tid  = threadIdx.x;
    const int lane = tid & 63;
    const int wid  = blockIdx.x * 4 + (tid >> 6);
    const int b    = wid >> 13;       // / 8192
    const int s    = wid & (L_SEQ - 1);
    const int nb   = nb_arr[b];

    if (blockIdx.x == 0 && tid == 0) {   // fused k_final (nb/len ready from k_scan)
        int nbt = 0, ln = 0;
        for (int i = 0; i < B_BATCH; ++i) { nbt += nb_arr[i]; ln += len_arr[i]; }
        const double k = (double)nbt, n = (double)ln;
        const double logp = lgamma(n + 1.0) - lgamma(k + 1.0) - lgamma(n - k + 1.0)
                            + k * log(0.2) + (n - k) * log(0.8);
        out_scal[0] = (float)(-logp / n);
        out_scal[1] = (float)nbt;
        out_scal[2] = (float)ln;
    }

    float4 res = {0.f, 0.f, 0.f, 0.f};
    if (s < nb) {
        const int start = (s == 0) ? 0 : starts[b * L_SEQ + s];
        const int end   = (s + 1 < nb) ? starts[b * L_SEQ + s + 1] : len_arr[b];
        float4 acc = {0.f, 0.f, 0.f, 0.f};
        for (int t = start; t < end; ++t) {
            const float4 v = ((const float4*)hidden)[(b * L_SEQ + t) * 64 + lane];
            acc.x += v.x; acc.y += v.y; acc.z += v.z; acc.w += v.w;
        }
        const float cntf = (float)(end - start);
        res.x = acc.x / cntf; res.y = acc.y / cntf; res.z = acc.z / cntf; res.w = acc.w / cntf;
    }
    ((float4*)pooled)[(size_t)wid * 64 + lane] = res;
}

extern "C" void kernel_launch(void* const* d_in, const int* in_sizes, int n_in,
                              void* d_out, int out_size, void* d_ws, size_t ws_size,
                              hipStream_t stream) {
    const float* hidden = (const float*)d_in[0];
    const float* Wq     = (const float*)d_in[1];
    const float* Wk     = (const float*)d_in[2];
    const float* noise  = (const float*)d_in[3];
    const float* mask   = (const float*)d_in[4];
    float* out = (float*)d_out;
    char* ws = (char*)d_ws;

    int*            starts = (int*)(ws);
    unsigned short* Bpack  = (unsigned short*)(ws + 262144);
    unsigned char*  hard   = (unsigned char*)(ws + 524288);
    int*            nb_arr = (int*)(ws + 589824);
    int*            len_arr= (int*)(ws + 589856);

    float* pooled = out;
    float* scal   = out + (size_t)BL * D_DIM;
    float* shortm = scal + 3;

    k_matMpack<<<256, 256, 0, stream>>>(Wq, Wk, Bpack);
    k_cosmfma <<<BL / 32, 256, 0, stream>>>(hidden, Bpack, noise, hard);
    k_scan    <<<B_BATCH, 1024, 0, stream>>>(mask, hard, starts, nb_arr, len_arr, shortm);
    k_pool    <<<BL / 4, 256, 0, stream>>>(hidden, starts, nb_arr, len_arr, pooled, scal);
}